// Round 11
// baseline (1365.773 us; speedup 1.0000x reference)
//
#include <hip/hip_runtime.h>
#include <cstdint>
#include <cstddef>

// ---------------- constants ----------------
#define NN 4096          // nodes
#define DH 128           // H1 == H2 == GRU_H
#define TP 4
#define ATT_S 4          // j-splits in attention
#define ATT_BM 32        // rows per attention block (32 -> 40KB LDS -> 4 blocks/CU)

typedef _Float16 f16x8 __attribute__((ext_vector_type(8)));
typedef float f32x4 __attribute__((ext_vector_type(4)));

// ---------------- pack adjacency into bitmask ----------------
__global__ __launch_bounds__(256) void pack_mask_k(const int* __restrict__ adj,
                                                   unsigned long long* __restrict__ mb) {
  int w = blockIdx.x * 4 + (threadIdx.x >> 6);
  int lane = threadIdx.x & 63;
  int v = adj[(size_t)w * 64 + lane];
  unsigned long long bits = __ballot(v > 0);
  if (lane == 0) mb[w] = bits;
}

// ---------------- MFMA fp32-via-f16-split GEMM: C = act(A@B + bias) ----------------
// 64x64 tile, BK=64, 4 waves (2x2), each wave a 32x32 quadrant.
// BHEAD=1: B is [2][K][128] (two head matrices concatenated along N=256).
template <int ACT, int BHEAD>
__global__ __launch_bounds__(256) void gemm_mfma_k(const float* __restrict__ A, const float* __restrict__ B,
                                                   const float* __restrict__ bias, float* __restrict__ C,
                                                   int M, int N, int K) {
  __shared__ _Float16 AH[64 * 64], AL[64 * 64];
  __shared__ _Float16 BH[64 * 64], BL[64 * 64];
  const int tid = threadIdx.x;
  const int bm = blockIdx.y * 64, bn = blockIdx.x * 64;
  const int arow = tid >> 2, akc = (tid & 3) * 16;
  const int bcol = tid & 63, bkc = (tid >> 6) * 16;
  const int w = tid >> 6, lane = tid & 63;
  const int wm = w >> 1, wn = w & 1;
  const int l15 = lane & 15, l4 = lane >> 4;
  f32x4 acc[2][2] = {};

  const float* Bp = B;
  int bcb = bn;
  if (BHEAD) { int hd = bn >> 7; Bp = B + (size_t)hd * K * 128; bcb = bn & 127; }
  const int ldb = BHEAD ? 128 : N;

  for (int k0 = 0; k0 < K; k0 += 64) {
    __syncthreads();
    // ---- stage A tile (f16 hi/lo split, swizzled) ----
    {
      const float* ar = A + (size_t)(bm + arow) * K;
      f16x8 hv[2], lv[2];
#pragma unroll
      for (int e = 0; e < 16; e++) {
        int gk = k0 + akc + e;
        float v = (gk < K) ? ar[gk] : 0.f;
        _Float16 hi = (_Float16)v;
        hv[e >> 3][e & 7] = hi;
        lv[e >> 3][e & 7] = (_Float16)(v - (float)hi);
      }
#pragma unroll
      for (int hf = 0; hf < 2; hf++) {
        int byt = ((arow * 64 + akc + hf * 8) * 2) ^ ((arow & 7) << 4);
        *(f16x8*)((char*)AH + byt) = hv[hf];
        *(f16x8*)((char*)AL + byt) = lv[hf];
      }
    }
    // ---- stage B^T tile ----
    {
      f16x8 hv[2], lv[2];
      const bool cok = (bcb + bcol) < ldb;
#pragma unroll
      for (int e = 0; e < 16; e++) {
        int gk = k0 + bkc + e;
        float v = (gk < K && cok) ? Bp[(size_t)gk * ldb + bcb + bcol] : 0.f;
        _Float16 hi = (_Float16)v;
        hv[e >> 3][e & 7] = hi;
        lv[e >> 3][e & 7] = (_Float16)(v - (float)hi);
      }
#pragma unroll
      for (int hf = 0; hf < 2; hf++) {
        int byt = ((bcol * 64 + bkc + hf * 8) * 2) ^ ((bcol & 7) << 4);
        *(f16x8*)((char*)BH + byt) = hv[hf];
        *(f16x8*)((char*)BL + byt) = lv[hf];
      }
    }
    __syncthreads();
    // ---- MFMA ----
#pragma unroll
    for (int kf = 0; kf < 2; kf++) {
      f16x8 ah[2], al[2], bh[2], bl[2];
#pragma unroll
      for (int m2 = 0; m2 < 2; m2++) {
        int r = wm * 32 + m2 * 16 + l15;
        int byt = ((r * 64 + kf * 32 + l4 * 8) * 2) ^ ((r & 7) << 4);
        ah[m2] = *(const f16x8*)((const char*)AH + byt);
        al[m2] = *(const f16x8*)((const char*)AL + byt);
      }
#pragma unroll
      for (int nf = 0; nf < 2; nf++) {
        int c = wn * 32 + nf * 16 + l15;
        int byt = ((c * 64 + kf * 32 + l4 * 8) * 2) ^ ((c & 7) << 4);
        bh[nf] = *(const f16x8*)((const char*)BH + byt);
        bl[nf] = *(const f16x8*)((const char*)BL + byt);
      }
#pragma unroll
      for (int m2 = 0; m2 < 2; m2++)
#pragma unroll
        for (int nf = 0; nf < 2; nf++) {
          acc[m2][nf] = __builtin_amdgcn_mfma_f32_16x16x32_f16(ah[m2], bh[nf], acc[m2][nf], 0, 0, 0);
          acc[m2][nf] = __builtin_amdgcn_mfma_f32_16x16x32_f16(ah[m2], bl[nf], acc[m2][nf], 0, 0, 0);
          acc[m2][nf] = __builtin_amdgcn_mfma_f32_16x16x32_f16(al[m2], bh[nf], acc[m2][nf], 0, 0, 0);
        }
    }
  }
  // ---- epilogue (C/D layout: col=lane&15, row=(lane>>4)*4+q) ----
#pragma unroll
  for (int m2 = 0; m2 < 2; m2++)
#pragma unroll
    for (int nf = 0; nf < 2; nf++) {
      int c = bn + wn * 32 + nf * 16 + l15;
      if (c < N) {
        float bv = bias ? bias[c] : 0.f;
#pragma unroll
        for (int q = 0; q < 4; q++) {
          int r = bm + wm * 32 + m2 * 16 + l4 * 4 + q;
          float v = acc[m2][nf][q] + bv;
          if (ACT == 1) v = (v >= 0.f) ? v : 0.01f * v;
          C[(size_t)r * N + c] = v;
        }
      }
    }
}

// ---------------- split-K GEMM: Cpart[z] = A[:, z*256:(z+1)*256] @ B ----------------
// Same structure as gemm_mfma_k; raw partial store (no bias/act). Used for the
// K~900 feature transforms where the (4, M/64) grid is occupancy-starved.
__global__ __launch_bounds__(256) void gemm_ksplit_k(const float* __restrict__ A, const float* __restrict__ B,
                                                     float* __restrict__ Cpart, int M, int N, int K) {
  __shared__ _Float16 AH[64 * 64], AL[64 * 64];
  __shared__ _Float16 BH[64 * 64], BL[64 * 64];
  const int tid = threadIdx.x;
  const int bm = blockIdx.y * 64, bn = blockIdx.x * 64;
  const int kbeg = blockIdx.z * 256;
  const int kend = min(K, kbeg + 256);
  float* C = Cpart + (size_t)blockIdx.z * M * N;
  const int arow = tid >> 2, akc = (tid & 3) * 16;
  const int bcol = tid & 63, bkc = (tid >> 6) * 16;
  const int w = tid >> 6, lane = tid & 63;
  const int wm = w >> 1, wn = w & 1;
  const int l15 = lane & 15, l4 = lane >> 4;
  f32x4 acc[2][2] = {};

  for (int k0 = kbeg; k0 < kend; k0 += 64) {
    __syncthreads();
    {
      const float* ar = A + (size_t)(bm + arow) * K;
      f16x8 hv[2], lv[2];
#pragma unroll
      for (int e = 0; e < 16; e++) {
        int gk = k0 + akc + e;
        float v = (gk < K) ? ar[gk] : 0.f;
        _Float16 hi = (_Float16)v;
        hv[e >> 3][e & 7] = hi;
        lv[e >> 3][e & 7] = (_Float16)(v - (float)hi);
      }
#pragma unroll
      for (int hf = 0; hf < 2; hf++) {
        int byt = ((arow * 64 + akc + hf * 8) * 2) ^ ((arow & 7) << 4);
        *(f16x8*)((char*)AH + byt) = hv[hf];
        *(f16x8*)((char*)AL + byt) = lv[hf];
      }
    }
    {
      f16x8 hv[2], lv[2];
      const bool cok = (bn + bcol) < N;
#pragma unroll
      for (int e = 0; e < 16; e++) {
        int gk = k0 + bkc + e;
        float v = (gk < K && cok) ? B[(size_t)gk * N + bn + bcol] : 0.f;
        _Float16 hi = (_Float16)v;
        hv[e >> 3][e & 7] = hi;
        lv[e >> 3][e & 7] = (_Float16)(v - (float)hi);
      }
#pragma unroll
      for (int hf = 0; hf < 2; hf++) {
        int byt = ((bcol * 64 + bkc + hf * 8) * 2) ^ ((bcol & 7) << 4);
        *(f16x8*)((char*)BH + byt) = hv[hf];
        *(f16x8*)((char*)BL + byt) = lv[hf];
      }
    }
    __syncthreads();
#pragma unroll
    for (int kf = 0; kf < 2; kf++) {
      f16x8 ah[2], al[2], bh[2], bl[2];
#pragma unroll
      for (int m2 = 0; m2 < 2; m2++) {
        int r = wm * 32 + m2 * 16 + l15;
        int byt = ((r * 64 + kf * 32 + l4 * 8) * 2) ^ ((r & 7) << 4);
        ah[m2] = *(const f16x8*)((const char*)AH + byt);
        al[m2] = *(const f16x8*)((const char*)AL + byt);
      }
#pragma unroll
      for (int nf = 0; nf < 2; nf++) {
        int c = wn * 32 + nf * 16 + l15;
        int byt = ((c * 64 + kf * 32 + l4 * 8) * 2) ^ ((c & 7) << 4);
        bh[nf] = *(const f16x8*)((const char*)BH + byt);
        bl[nf] = *(const f16x8*)((const char*)BL + byt);
      }
#pragma unroll
      for (int m2 = 0; m2 < 2; m2++)
#pragma unroll
        for (int nf = 0; nf < 2; nf++) {
          acc[m2][nf] = __builtin_amdgcn_mfma_f32_16x16x32_f16(ah[m2], bh[nf], acc[m2][nf], 0, 0, 0);
          acc[m2][nf] = __builtin_amdgcn_mfma_f32_16x16x32_f16(ah[m2], bl[nf], acc[m2][nf], 0, 0, 0);
          acc[m2][nf] = __builtin_amdgcn_mfma_f32_16x16x32_f16(al[m2], bh[nf], acc[m2][nf], 0, 0, 0);
        }
    }
  }
#pragma unroll
  for (int m2 = 0; m2 < 2; m2++)
#pragma unroll
    for (int nf = 0; nf < 2; nf++) {
      int c = bn + wn * 32 + nf * 16 + l15;
      if (c < N) {
#pragma unroll
        for (int q = 0; q < 4; q++) {
          int r = bm + wm * 32 + m2 * 16 + l4 * 4 + q;
          C[(size_t)r * N + c] = acc[m2][nf][q];
        }
      }
    }
}

// ---------------- sum split-K partials + bias (feature transform, N=256) ----------------
__global__ __launch_bounds__(256) void ksum_k(const float* __restrict__ part, const float* __restrict__ bias,
                                              float* __restrict__ C, int KS) {
  int idx = blockIdx.x * 256 + threadIdx.x;   // over NN*256
  const size_t MN = (size_t)NN * 256;
  float s = bias[idx & 255];
  for (int i = 0; i < KS; i++) s += part[(size_t)i * MN + idx];
  C[idx] = s;
}

// ---------------- el/er for both heads (hcat layout [NN][256]) ----------------
__global__ __launch_bounds__(256) void eler_k(const float* __restrict__ hcat, const float* __restrict__ a,
                                              float* __restrict__ el, float* __restrict__ er) {
  int head = blockIdx.y;
  const float* ah = a + (size_t)head * 256;
  int row = blockIdx.x * 4 + (threadIdx.x >> 6);
  int lane = threadIdx.x & 63;
  const float* hr = hcat + (size_t)row * 256 + head * 128;
  float h0 = hr[lane], h1 = hr[lane + 64];
  float pe = h0 * ah[lane] + h1 * ah[lane + 64];
  float pr = h0 * ah[128 + lane] + h1 * ah[192 + lane];
#pragma unroll
  for (int off = 32; off >= 1; off >>= 1) {
    pe += __shfl_xor(pe, off, 64);
    pr += __shfl_xor(pr, off, 64);
  }
  if (lane == 0) { el[(size_t)head * NN + row] = pe; er[(size_t)head * NN + row] = pr; }
}

// ---------------- exact masked row max: m = leaky(el + max_masked(er)) ----------------
__global__ __launch_bounds__(256) void rowmax_k(const float* __restrict__ el, const float* __restrict__ er,
                                                const unsigned long long* __restrict__ mb,
                                                float* __restrict__ mrow) {
  int head = blockIdx.y;
  int row = blockIdx.x * 4 + (threadIdx.x >> 6);
  int lane = threadIdx.x & 63;
  const float* erh = er + (size_t)head * NN;
  const unsigned long long* mr = mb + (size_t)row * 64;
  float mx = -INFINITY;
  for (int i = 0; i < 64; i++) {
    unsigned long long w = mr[i];
    float v = erh[i * 64 + lane];
    mx = fmaxf(mx, ((w >> lane) & 1ull) ? v : -INFINITY);
  }
#pragma unroll
  for (int off = 32; off >= 1; off >>= 1) mx = fmaxf(mx, __shfl_xor(mx, off, 64));
  if (lane == 0) {
    float s = el[(size_t)head * NN + row] + mx;
    mrow[(size_t)head * NN + row] = fmaxf(s, 0.2f * s);
  }
}

// ---------------- pre-split + pre-transpose + pre-swizzle H into f16 tiles ----------------
// Output tiles: per (head, jblk) a 16KB byte image matching gat's swizzled LDS layout:
//   element (c,k) of H^T at byte ((c*64+k)*2) ^ ((c&7)<<4).
__global__ __launch_bounds__(256) void hsplit_k(const float* __restrict__ hcat,
                                                _Float16* __restrict__ HTH, _Float16* __restrict__ HTL) {
  const int jblk = blockIdx.x;   // 0..63
  const int head = blockIdx.y;   // 0..1
  const int tid = threadIdx.x;
  const int c = tid & 127;
  const size_t tileBase = ((size_t)head * (NN / 64) + jblk) * 8192;  // f16 elements
#pragma unroll
  for (int kq = 0; kq < 4; kq++) {
    int k0 = (tid >> 7) * 32 + kq * 8;
    f16x8 hv, lv;
#pragma unroll
    for (int e = 0; e < 8; e++) {
      float v = hcat[(size_t)(jblk * 64 + k0 + e) * 256 + head * 128 + c];
      _Float16 hi = (_Float16)v;
      hv[e] = hi;
      lv[e] = (_Float16)(v - (float)hi);
    }
    int byt = ((c * 64 + k0) * 2) ^ ((c & 7) << 4);
    *(f16x8*)((char*)(HTH + tileBase) + byt) = hv;
    *(f16x8*)((char*)(HTL + tileBase) + byt) = lv;
  }
}

// ---------------- MFMA flash-GAT: accumulate O_part = P @ H, Z_part ----------------
// ATT_BM=32 rows/block, 40KB LDS -> 4 blocks/CU. Each wave owns a 16x64 output quadrant.
__global__ __launch_bounds__(256) void gat_mfma_k(const _Float16* __restrict__ HTH_g,
                                                  const _Float16* __restrict__ HTL_g,
                                                  const float* __restrict__ el, const float* __restrict__ er,
                                                  const float* __restrict__ mrow,
                                                  const unsigned long long* __restrict__ mb,
                                                  float* __restrict__ Opart, float* __restrict__ Zpart) {
  const int split = blockIdx.x;
  const int mblk = blockIdx.y;     // 0..127
  const int head = blockIdx.z;
  const float* elh = el + (size_t)head * NN;
  const float* erh = er + (size_t)head * NN;
  const float* mh = mrow + (size_t)head * NN;
  float* Op = Opart + ((size_t)head * ATT_S + split) * NN * DH;
  float* Zp = Zpart + ((size_t)head * ATT_S + split) * NN;

  __shared__ _Float16 PH[ATT_BM * 64];   // 4 KB
  __shared__ _Float16 PL[ATT_BM * 64];   // 4 KB
  __shared__ _Float16 HH[128 * 64];      // 16 KB (byte image from HTH_g)
  __shared__ _Float16 HL[128 * 64];      // 16 KB   -> 40KB total; zred aliases PH

  const int tid = threadIdx.x;
  const int prow = tid >> 3;        // 0..31
  const int pk0 = (tid & 7) * 8;    // col octet within 64-j tile
  const int grow = mblk * ATT_BM + prow;
  const float el_r = elh[grow];
  const float m_r = mh[grow];
  const int w = tid >> 6, lane = tid & 63;
  const int wm = w >> 1, wn = w & 1;
  const int l15 = lane & 15, l4 = lane >> 4;

  f32x4 acc[4] = {};                // nf = 0..3 (wave quadrant: 16 rows x 64 cols)
  float zacc = 0.f;
  const int jbase = split * (NN / ATT_S);

  for (int jt = 0; jt < NN / ATT_S; jt += 64) {
    const int j0 = jbase + jt;
    const int jblk = j0 >> 6;
    const char* srcH = (const char*)(HTH_g + ((size_t)head * (NN / 64) + jblk) * 8192);
    const char* srcL = (const char*)(HTL_g + ((size_t)head * (NN / 64) + jblk) * 8192);
    __syncthreads();   // previous MFMA done reading LDS

    // ---- issue H-tile loads (latency hidden under P-compute) ----
    f16x8 rh[4], rl[4];
#pragma unroll
    for (int i = 0; i < 4; i++) {
      rh[i] = *(const f16x8*)(srcH + (tid + i * 256) * 16);
      rl[i] = *(const f16x8*)(srcL + (tid + i * 256) * 16);
    }

    // ---- compute P tile (32 x 64): 8 values/thread, f16 hi/lo, swizzled ----
    {
      unsigned long long wbits = mb[(size_t)grow * 64 + jblk];
      float er_v[8];
      float4 t0 = *(const float4*)&erh[j0 + pk0];
      float4 t1 = *(const float4*)&erh[j0 + pk0 + 4];
      er_v[0] = t0.x; er_v[1] = t0.y; er_v[2] = t0.z; er_v[3] = t0.w;
      er_v[4] = t1.x; er_v[5] = t1.y; er_v[6] = t1.z; er_v[7] = t1.w;
      f16x8 hv, lv;
#pragma unroll
      for (int e = 0; e < 8; e++) {
        float sr = el_r + er_v[e];
        float s = fmaxf(sr, 0.2f * sr);
        float p = ((wbits >> (pk0 + e)) & 1ull) ? __expf(s - m_r) : 0.f;
        zacc += p;
        _Float16 hi = (_Float16)p;
        hv[e] = hi;
        lv[e] = (_Float16)(p - (float)hi);
      }
      int byt = (((prow * 64) + pk0) * 2) ^ ((prow & 7) << 4);
      *(f16x8*)((char*)PH + byt) = hv;
      *(f16x8*)((char*)PL + byt) = lv;
    }

    // ---- write H tile to LDS (verbatim byte copy; swizzle baked into data) ----
#pragma unroll
    for (int i = 0; i < 4; i++) {
      *(f16x8*)((char*)HH + (tid + i * 256) * 16) = rh[i];
      *(f16x8*)((char*)HL + (tid + i * 256) * 16) = rl[i];
    }
    __syncthreads();

    // ---- MFMA: acc += Phi*Hhi + Phi*Hlo + Plo*Hhi ----
#pragma unroll
    for (int kf = 0; kf < 2; kf++) {
      int r = wm * 16 + l15;
      int ab = ((r * 64 + kf * 32 + l4 * 8) * 2) ^ ((r & 7) << 4);
      f16x8 ah = *(const f16x8*)((const char*)PH + ab);
      f16x8 al = *(const f16x8*)((const char*)PL + ab);
#pragma unroll
      for (int nf = 0; nf < 4; nf++) {
        int bc = wn * 64 + nf * 16 + l15;
        int bb = ((bc * 64 + kf * 32 + l4 * 8) * 2) ^ ((bc & 7) << 4);
        f16x8 bh = *(const f16x8*)((const char*)HH + bb);
        f16x8 bl = *(const f16x8*)((const char*)HL + bb);
        acc[nf] = __builtin_amdgcn_mfma_f32_16x16x32_f16(ah, bh, acc[nf], 0, 0, 0);
        acc[nf] = __builtin_amdgcn_mfma_f32_16x16x32_f16(ah, bl, acc[nf], 0, 0, 0);
        acc[nf] = __builtin_amdgcn_mfma_f32_16x16x32_f16(al, bh, acc[nf], 0, 0, 0);
      }
    }
  }

  // ---- Z reduce (zred aliases PH; barrier first so all MFMA reads are done) ----
  __syncthreads();
  float* zred = (float*)PH;        // 32 x 8 floats = 1KB
  zred[prow * 8 + (tid & 7)] = zacc;
  __syncthreads();
  if (tid < ATT_BM) {
    float z = 0.f;
#pragma unroll
    for (int i = 0; i < 8; i++) z += zred[tid * 8 + i];
    Zp[mblk * ATT_BM + tid] = z;
  }

  // ---- O_part store (C/D layout: col=lane&15, row=(lane>>4)*4+q) ----
#pragma unroll
  for (int nf = 0; nf < 4; nf++)
#pragma unroll
    for (int q = 0; q < 4; q++) {
      int r = mblk * ATT_BM + wm * 16 + l4 * 4 + q;
      int c = wn * 64 + nf * 16 + l15;
      Op[(size_t)r * DH + c] = acc[nf][q];
    }
}

// ---------------- combine partials -> head mean (+optional ELU) ----------------
template <int DO_ELU>
__global__ __launch_bounds__(256) void combine_k(const float* __restrict__ Opart,
                                                 const float* __restrict__ Zpart,
                                                 const float* __restrict__ bvec,
                                                 float* __restrict__ out) {
  int row = blockIdx.x * 4 + (threadIdx.x >> 6);
  int lane = threadIdx.x & 63;
  int c = lane * 2;
  float o0 = 0.f, o1 = 0.f;
#pragma unroll
  for (int hd = 0; hd < 2; hd++) {
    float a0 = 0.f, a1 = 0.f, Z = 0.f;
#pragma unroll
    for (int s = 0; s < ATT_S; s++) {
      const float* Op = Opart + ((size_t)hd * ATT_S + s) * NN * DH;
      float2 t = *(const float2*)&Op[(size_t)row * DH + c];
      a0 += t.x; a1 += t.y;
      Z += Zpart[((size_t)hd * ATT_S + s) * NN + row];
    }
    float invZ = 1.f / Z;
    float v0 = a0 * invZ, v1 = a1 * invZ;
    v0 = fmaxf(v0, 0.2f * v0);
    v1 = fmaxf(v1, 0.2f * v1);
    float ss = v0 * v0 + v1 * v1;
#pragma unroll
    for (int off = 32; off >= 1; off >>= 1) ss += __shfl_xor(ss, off, 64);
    float sc_ = 1.f / fmaxf(sqrtf(ss), 1e-12f);
    o0 += 0.5f * (v0 * sc_ + bvec[hd * DH + c]);
    o1 += 0.5f * (v1 * sc_ + bvec[hd * DH + c + 1]);
  }
  if (DO_ELU) {
    o0 = (o0 > 0.f) ? o0 : expm1f(o0);
    o1 = (o1 > 0.f) ? o1 : expm1f(o1);
  }
  float2 st = {o0, o1};
  *(float2*)&out[(size_t)row * DH + c] = st;
}

// ---------------- gather tf/tg rows into GRU input ----------------
__global__ __launch_bounds__(256) void gather_k(const float* __restrict__ tf, const float* __restrict__ tg,
                                                const int* __restrict__ ts, float* __restrict__ hx_t) {
  int idx = blockIdx.x * 256 + threadIdx.x;
  int e = idx >> 5, c = idx & 31;
  int src = (c < 16) ? ts[e * 2] : ts[e * 2 + 1];
  float v = (c < 16) ? tf[(size_t)src * 16 + c] : tg[(size_t)src * 16 + (c - 16)];
  hx_t[idx] = v;
}

// ---------------- GRU gate fusion ----------------
__global__ __launch_bounds__(256) void gru_gate_k(const float* __restrict__ gi, const float* __restrict__ gh,
                                                  const float* __restrict__ hprev, float* __restrict__ hout) {
  int idx = blockIdx.x * 256 + threadIdx.x;
  int b = idx >> 7, c = idx & 127;
  const float* gib = gi + (size_t)b * 384;
  const float* ghb = gh + (size_t)b * 384;
  float ir = gib[c], iz = gib[128 + c], in_ = gib[256 + c];
  float hr = ghb[c], hz = ghb[128 + c], hn = ghb[256 + c];
  float rr = 1.f / (1.f + __expf(-(ir + hr)));
  float zz = 1.f / (1.f + __expf(-(iz + hz)));
  float nn_ = tanhf(in_ + rr * hn);
  hout[idx] = (1.f - zz) * nn_ + zz * hprev[idx];
}

// ---------------- GRU gate, t=0 (hprev = 0 -> gh = bhh) ----------------
__global__ __launch_bounds__(256) void gru_gate0_k(const float* __restrict__ gi, const float* __restrict__ bhh,
                                                   float* __restrict__ hout) {
  int idx = blockIdx.x * 256 + threadIdx.x;
  int b = idx >> 7, c = idx & 127;
  const float* gib = gi + (size_t)b * 384;
  float ir = gib[c], iz = gib[128 + c], in_ = gib[256 + c];
  float hr = bhh[c], hz = bhh[128 + c], hn = bhh[256 + c];
  float rr = 1.f / (1.f + __expf(-(ir + hr)));
  float zz = 1.f / (1.f + __expf(-(iz + hz)));
  float nn_ = tanhf(in_ + rr * hn);
  hout[idx] = (1.f - zz) * nn_;
}

// ---------------- temporal attention pooling ----------------
__global__ __launch_bounds__(256) void attpool_k(const float* __restrict__ z, const float* __restrict__ y,
                                                 float* __restrict__ o) {
  int idx = blockIdx.x * 256 + threadIdx.x;
  const size_t S = (size_t)NN * DH;
  float z0 = z[idx], z1 = z[idx + S], z2 = z[idx + 2 * S], z3 = z[idx + 3 * S];
  float mx = fmaxf(fmaxf(z0, z1), fmaxf(z2, z3));
  float e0 = __expf(z0 - mx), e1 = __expf(z1 - mx), e2 = __expf(z2 - mx), e3 = __expf(z3 - mx);
  float inv = 1.f / (e0 + e1 + e2 + e3);
  o[idx] = (e0 * y[idx] + e1 * y[idx + S] + e2 * y[idx + 2 * S] + e3 * y[idx + 3 * S]) * inv;
}

// ---------------- final projection ----------------
__global__ __launch_bounds__(256) void final_k(const float* __restrict__ at, const float* __restrict__ fow,
                                               const float* __restrict__ fob, float* __restrict__ out) {
  int row = blockIdx.x * 4 + (threadIdx.x >> 6);
  int lane = threadIdx.x & 63;
  const float* ar = at + (size_t)row * DH;
  float p = ar[lane] * fow[lane] + ar[lane + 64] * fow[lane + 64];
#pragma unroll
  for (int off = 32; off >= 1; off >>= 1) p += __shfl_xor(p, off, 64);
  if (lane == 0) out[row] = p + fob[0];
}

// ---------------- host ----------------
static inline void run_gemm(int act, const float* A, const float* B, const float* bias, float* C,
                            int M, int N, int K, hipStream_t s) {
  dim3 g((N + 63) / 64, M / 64), b(256);
  if (act == 0) gemm_mfma_k<0, 0><<<g, b, 0, s>>>(A, B, bias, C, M, N, K);
  else          gemm_mfma_k<1, 0><<<g, b, 0, s>>>(A, B, bias, C, M, N, K);
}
static inline void run_proj(const float* A, const float* B, float* C, int K, hipStream_t s) {
  // B = [2][K][128]; C = [NN][256]
  gemm_mfma_k<0, 1><<<dim3(4, NN / 64), 256, 0, s>>>(A, B, nullptr, C, NN, 256, K);
}

extern "C" void kernel_launch(void* const* d_in, const int* in_sizes, int n_in,
                              void* d_out, int out_size, void* d_ws, size_t ws_size,
                              hipStream_t stream) {
  const float* x[4]  = {(const float*)d_in[0], (const float*)d_in[1], (const float*)d_in[2], (const float*)d_in[3]};
  const int* adj     = (const int*)d_in[4];
  const int* tsample = (const int*)d_in[5];
  const float* nw[4] = {(const float*)d_in[6], (const float*)d_in[8], (const float*)d_in[10], (const float*)d_in[12]};
  const float* nb[4] = {(const float*)d_in[7], (const float*)d_in[9], (const float*)d_in[11], (const float*)d_in[13]};
  const float* W1 = (const float*)d_in[14];
  const float* a1 = (const float*)d_in[15];
  const float* b1 = (const float*)d_in[16];
  const float* W2 = (const float*)d_in[17];
  const float* a2 = (const float*)d_in[18];
  const float* b2 = (const float*)d_in[19];
  const float* tfw1 = (const float*)d_in[20]; const float* tfb1 = (const float*)d_in[21];
  const float* tfw2 = (const float*)d_in[22]; const float* tfb2 = (const float*)d_in[23];
  const float* tgw1 = (const float*)d_in[24]; const float* tgb1 = (const float*)d_in[25];
  const float* tgw2 = (const float*)d_in[26]; const float* tgb2 = (const float*)d_in[27];
  const float* wih0 = (const float*)d_in[28]; const float* whh0 = (const float*)d_in[29];
  const float* bih0 = (const float*)d_in[30]; const float* bhh0 = (const float*)d_in[31];
  const float* wih1 = (const float*)d_in[32]; const float* whh1 = (const float*)d_in[33];
  const float* bih1 = (const float*)d_in[34]; const float* bhh1 = (const float*)d_in[35];
  const float* attw = (const float*)d_in[36]; const float* attb = (const float*)d_in[37];
  const float* fow  = (const float*)d_in[38]; const float* fob  = (const float*)d_in[39];
  float* out = (float*)d_out;

  // workspace layout (bump allocator, 256B aligned)
  char* base = (char*)d_ws;
  size_t off = 0;
  auto alloc = [&](size_t bytes) -> void* {
    void* p = base + off;
    off += (bytes + 255) & ~(size_t)255;
    return p;
  };
  const size_t SN = (size_t)NN * DH;
  unsigned long long* mbits = (unsigned long long*)alloc((size_t)NN * 64 * 8);  // 2MB
  float* ebuf = (float*)alloc((size_t)NN * 256 * 4);  // 4MB; reused as HTH/HTL after W-proj consumes it
  float* hcat = (float*)alloc((size_t)NN * 256 * 4);  // 4MB  [NN][256] both heads
  float* el   = (float*)alloc((size_t)2 * NN * 4);
  float* er   = (float*)alloc((size_t)2 * NN * 4);
  float* mrowb= (float*)alloc((size_t)2 * NN * 4);
  float* bufA = (float*)alloc(SN * 4);                // embed
  float* bufB = (float*)alloc(SN * 4);                // layer-1 out (post-ELU)
  float* tmp1 = (float*)alloc((size_t)NN * 64 * 4);
  float* tfb_ = (float*)alloc((size_t)NN * 16 * 4);
  float* tgb_ = (float*)alloc((size_t)NN * 16 * 4);
  float* hx   = (float*)alloc((size_t)TP * NN * 32 * 4);  // 2MB
  float* y0   = (float*)alloc((size_t)TP * SN * 4);       // 8MB  } Opart / ksplit partials alias y0+y1
  float* y1   = (float*)alloc((size_t)TP * SN * 4);       // 8MB  }
  float* gi   = (float*)alloc((size_t)NN * 384 * 4);      // 6MB  } Zpart / zatt alias gi(+gh)
  float* gh   = (float*)alloc((size_t)NN * 384 * 4);      // 6MB
  float* Opart = y0;       // [2][ATT_S][NN][DH] fp32 = 16MB, dead before GRU writes y0/y1
  float* kpart = y0;       // split-K partials (<=16MB); dead before gat writes Opart
  float* Zpart = gi;       // [2][ATT_S][NN] = 128KB, dead before GRU writes gi
  float* zatt   = gi;      // pooling scratch (8MB over gi+gh, post-GRU)
  float* attout = hcat;    // pooled output (hcat dead post-GAT)
  // H pre-split tiles alias ebuf (4MB = 2MB + 2MB): ebuf is consumed by the W-proj
  // GEMM before hsplit_k writes these (stream-ordered).
  _Float16* HTH = (_Float16*)ebuf;
  _Float16* HTL = HTH + (size_t)2 * NN * 128;   // 1M f16 = 2MB each

  const int TD[4] = {933, 303, 683, 798};

  pack_mask_k<<<(NN * 64) / 4, 256, 0, stream>>>(adj, mbits);

  for (int t = 0; t < TP; t++) {
    // e = x_t @ nw_t + nb_t    [4096 x 256]   — split-K for occupancy (K up to 933)
    int KS = (TD[t] + 255) / 256;
    gemm_ksplit_k<<<dim3(4, NN / 64, KS), 256, 0, stream>>>(x[t], nw[t], kpart, NN, 256, TD[t]);
    ksum_k<<<(NN * 256) / 256, 256, 0, stream>>>(kpart, nb[t], ebuf, KS);

    // ---- GAT layer 1 (2 heads, mean, +ELU) ----
    run_proj(ebuf, W1, hcat, 256, stream);     // both heads, reads ebuf fully
    hsplit_k<<<dim3(NN / 64, 2), 256, 0, stream>>>(hcat, HTH, HTL);   // overwrites ebuf area
    eler_k<<<dim3(NN / 4, 2), 256, 0, stream>>>(hcat, a1, el, er);
    rowmax_k<<<dim3(NN / 4, 2), 256, 0, stream>>>(el, er, mbits, mrowb);
    gat_mfma_k<<<dim3(ATT_S, NN / ATT_BM, 2), 256, 0, stream>>>(HTH, HTL, el, er, mrowb, mbits, Opart, Zpart);
    combine_k<1><<<NN / 4, 256, 0, stream>>>(Opart, Zpart, b1, bufB);

    // ---- GAT layer 2 (2 heads, mean) ----
    run_proj(bufB, W2, hcat, 128, stream);
    hsplit_k<<<dim3(NN / 64, 2), 256, 0, stream>>>(hcat, HTH, HTL);
    eler_k<<<dim3(NN / 4, 2), 256, 0, stream>>>(hcat, a2, el, er);
    rowmax_k<<<dim3(NN / 4, 2), 256, 0, stream>>>(el, er, mbits, mrowb);
    gat_mfma_k<<<dim3(ATT_S, NN / ATT_BM, 2), 256, 0, stream>>>(HTH, HTL, el, er, mrowb, mbits, Opart, Zpart);
    combine_k<0><<<NN / 4, 256, 0, stream>>>(Opart, Zpart, b2, bufA);

    // ---- tf / tg MLPs (leaky 0.01) ----
    run_gemm(1, bufA, tfw1, tfb1, tmp1, NN, 64, DH, stream);
    run_gemm(1, tmp1, tfw2, tfb2, tfb_, NN, 16, 64, stream);
    run_gemm(1, bufA, tgw1, tgb1, tmp1, NN, 64, DH, stream);
    run_gemm(1, tmp1, tgw2, tgb2, tgb_, NN, 16, 64, stream);
    gather_k<<<(NN * 32) / 256, 256, 0, stream>>>(tfb_, tgb_, tsample, hx + (size_t)t * NN * 32);
  }

  // GRU layer 0: input 32 -> 128   (t=0: hprev=0 -> gh = bhh, no GEMM)
  run_gemm(0, hx, wih0, bih0, gi, NN, 384, 32, stream);
  gru_gate0_k<<<(int)(SN / 256), 256, 0, stream>>>(gi, bhh0, y0);
  for (int t = 1; t < TP; t++) {
    const float* hprev = y0 + (size_t)(t - 1) * SN;
    run_gemm(0, hx + (size_t)t * NN * 32, wih0, bih0, gi, NN, 384, 32, stream);
    run_gemm(0, hprev, whh0, bhh0, gh, NN, 384, DH, stream);
    gru_gate_k<<<(int)(SN / 256), 256, 0, stream>>>(gi, gh, hprev, y0 + (size_t)t * SN);
  }
  // GRU layer 1: 128 -> 128
  run_gemm(0, y0, wih1, bih1, gi, NN, 384, DH, stream);
  gru_gate0_k<<<(int)(SN / 256), 256, 0, stream>>>(gi, bhh1, y1);
  for (int t = 1; t < TP; t++) {
    const float* hprev = y1 + (size_t)(t - 1) * SN;
    run_gemm(0, y0 + (size_t)t * SN, wih1, bih1, gi, NN, 384, DH, stream);
    run_gemm(0, hprev, whh1, bhh1, gh, NN, 384, DH, stream);
    gru_gate_k<<<(int)(SN / 256), 256, 0, stream>>>(gi, gh, hprev, y1 + (size_t)t * SN);
  }

  // temporal attention pooling: one batched GEMM over all 4 timesteps
  run_gemm(0, y1, attw, attb, zatt, TP * NN, DH, DH, stream);
  attpool_k<<<(int)(SN / 256), 256, 0, stream>>>(zatt, y1, attout);
  final_k<<<NN / 4, 256, 0, stream>>>(attout, fow, fob, out);
}